// Round 4
// baseline (185.745 us; speedup 1.0000x reference)
//
#include <hip/hip_runtime.h>

// Fused CNN, conv2 via bf16 MFMA (16x16x32).
// R7: occupancy push to the HW max (8 blocks/CU = 32 waves/CU):
//   (1) __launch_bounds__(256,8) pins VGPR<=64 (R4/R6 lesson: 65..128 VGPR
//       -> 4 waves/SIMD cliff; the allocator drifts past 64 unless forced).
//   (2) LDS 29696 -> 20000 B (rounds to 20480 = 163840/8 exactly):
//       h1t stride 72->64 shorts, img stored bf16.
//   (3) stride 64 = 0 mod 32 banks would make stage-2 ds_read_b128 a 16-way
//       conflict -> XOR swizzle short_idx ^= (pos&7)<<3 (T2). Verified: the
//       64 lanes of each b128 read distribute exactly 8 per 4-bank group =
//       the 8-phase minimum, i.e. conflict-free; same involution on write.
//   Keeps: R3 stage-1 scalar ring (proven 64-VGPR fit), cbuf bf16 stride 101,
//   h2t stride 65, single-barrier structure (R5 lesson: no per-row barriers).

typedef __attribute__((ext_vector_type(8))) short short8;   // 8 x bf16 (4 VGPRs)
typedef __attribute__((ext_vector_type(4))) float f32x4;

__device__ inline short f2bf(float f) {   // fp32 -> bf16, round-to-nearest-even
    union { float f; unsigned u; } v; v.f = f;
    unsigned r = (v.u + 0x7FFFu + ((v.u >> 16) & 1u)) >> 16;
    return (short)r;
}
__device__ inline float bf2f(short s) {
    union { unsigned u; float f; } v; v.u = ((unsigned)(unsigned short)s) << 16;
    return v.f;
}

// w2r[s][cout][cin] (bf16), s = ky*3+kx: MFMA A-fragments contiguous in cin.
__global__ __launch_bounds__(256) void prep_w2(const float* __restrict__ w2,
                                               short* __restrict__ w2r) {
    int i = blockIdx.x * 256 + threadIdx.x;      // 9*64*64 = 36864
    if (i >= 36864) return;
    int s = i >> 12, cout = (i >> 6) & 63, cin = i & 63;
    w2r[i] = f2bf(w2[cout * 576 + cin * 9 + s]);
}

__global__ __launch_bounds__(256, 8) void convnet_fused(
    const float* __restrict__ x,   // [B,1,28,28]
    const float* __restrict__ w1,  // [64,1,3,3]
    const float* __restrict__ b1,  // [64]
    const short* __restrict__ w2r, // [9][64][64] bf16 (prep)
    const float* __restrict__ b2,  // [64]
    const float* __restrict__ w3,  // [10,64,4,4]
    const float* __restrict__ b3,  // [10]
    float* __restrict__ out)       // [B,10]
{
    // Overlay plan (bytes):
    //   [0..18432)     h1t bf16 [144 pos][64 cin], XOR-swizzled (pos&7)<<3
    //   [18432..20000) imgbf bf16 [784]
    //   stage2+ (h1t/imgbf dead after mid-stage-2 barrier):
    //   [0..12928)     cbuf bf16 [64][101]
    //   [12928..17088) h2t fp32 [16 pos][65 stride]
    //   [0..640)       stage-3 partials (cbuf dead by then)
    __shared__ float lds_f[5000];                // 20000 B -> 8 blocks/CU
    short* h1t   = (short*)lds_f;
    short* imgbf = (short*)(lds_f + 4608);
    short* cbuf  = (short*)lds_f;                // bf16 [64][101]
    float* h2t   = lds_f + 3232;
    float* prt   = lds_f;

    const int n_img = blockIdx.x;
    const int t = threadIdx.x;
    const int c = t >> 2;        // 0..63
    const int q = t & 3;         // quadrant

    // ---- load input image -> bf16 ----
    const float* img_g = x + (size_t)n_img * 784;
    for (int i = t; i < 784; i += 256) imgbf[i] = f2bf(img_g[i]);
    __syncthreads();

    // ---- stage 1: conv1 + pool 3x3 s2 + relu -> h1t[pos][c] (bf16), no recompute ----
    {
        const int oy = (q >> 1) * 6, ox = (q & 1) * 6;   // pooled quadrant origin
        const int iy0 = 2 * oy, ix0 = 2 * ox;            // input/conv region origin (ix0 even)
        float w[9];
        #pragma unroll
        for (int k = 0; k < 9; ++k) w[k] = w1[c * 9 + k];
        const float bias = b1[c];

        float in0[15], in1[15], in2[15];                 // ring of 3 input rows

        // bf16 row load: 8 dword reads -> 15 floats (base is even)
        #define LOADROW(dst, row) do { \
            const unsigned* p32 = (const unsigned*)(imgbf + (row) * 28 + ix0); \
            _Pragma("unroll") \
            for (int d = 0; d < 8; ++d) { \
                const unsigned u = p32[d]; \
                union { unsigned u; float f; } lo, hi; \
                lo.u = u << 16; hi.u = u & 0xFFFF0000u; \
                if (2 * d < 15) (dst)[2 * d] = lo.f; \
                if (2 * d + 1 < 15) (dst)[2 * d + 1] = hi.f; \
            } } while (0)

        LOADROW(in0, iy0 + 0);
        LOADROW(in1, iy0 + 1);
        float cm[3][6];                                  // colmax ring (3 conv rows)

        #pragma unroll
        for (int r = 0; r < 13; ++r) {                   // conv rows, computed once
            LOADROW(in2, iy0 + r + 2);
            #pragma unroll
            for (int px = 0; px < 6; ++px) cm[r % 3][px] = -1e30f;
            #pragma unroll
            for (int xx = 0; xx < 13; ++xx) {
                float a = bias;
                #pragma unroll
                for (int j = 0; j < 3; ++j) {
                    a += in0[xx + j] * w[j];
                    a += in1[xx + j] * w[3 + j];
                    a += in2[xx + j] * w[6 + j];
                }
                // fold conv value into colmax: px with 2px <= xx <= 2px+2
                if ((xx & 1) == 0) {
                    if (xx >= 2 && xx <= 12) cm[r % 3][xx / 2 - 1] = fmaxf(cm[r % 3][xx / 2 - 1], a);
                    if (xx <= 10)            cm[r % 3][xx / 2]     = fmaxf(cm[r % 3][xx / 2], a);
                } else {
                    cm[r % 3][xx / 2] = fmaxf(cm[r % 3][xx / 2], a);
                }
            }
            if (r >= 2 && (r & 1) == 0) {                // pooled row py = r/2 - 1 complete
                const int py = r / 2 - 1;
                #pragma unroll
                for (int px = 0; px < 6; ++px) {
                    float m = fmaxf(fmaxf(cm[0][px], cm[1][px]), cm[2][px]);
                    const int pos = (oy + py) * 12 + ox + px;
                    h1t[pos * 64 + (c ^ ((pos & 7) << 3))] = f2bf(fmaxf(m, 0.0f));
                }
            }
            #pragma unroll
            for (int s = 0; s < 15; ++s) { in0[s] = in1[s]; in1[s] = in2[s]; }
        }
        #undef LOADROW
    }
    __syncthreads();

    // ---- stage 2: conv2 as MFMA GEMM (M=64 cout, N=100 pad 112, K=576) ----
    const int wv = t >> 6, lane = t & 63;
    const int quad = lane >> 4, mrow = lane & 15;
    {
        int pos_b[7];
        #pragma unroll
        for (int nt = 0; nt < 7; ++nt) {
            int n = nt * 16 + mrow; if (n > 99) n = 99;   // clamp pad cols (discarded)
            int y = n / 10, xx = n - y * 10;
            pos_b[nt] = y * 12 + xx;
        }
        f32x4 acc[7];
        #pragma unroll
        for (int nt = 0; nt < 7; ++nt) acc[nt] = (f32x4){0.f, 0.f, 0.f, 0.f};

        #pragma unroll
        for (int ks = 0; ks < 18; ++ks) {
            const int s = ks >> 1, h = ks & 1;
            const int ky = s / 3, kx = s - ky * 3;
            const int koff = ky * 12 + kx;
            const int hoff = h * 32 + quad * 8;
            const short8 a = *(const short8*)(w2r + s * 4096 + (wv * 16 + mrow) * 64
                                              + h * 32 + quad * 8);
            #pragma unroll
            for (int nt = 0; nt < 7; ++nt) {
                const int pos = pos_b[nt] + koff;
                const short8 b = *(const short8*)(h1t + pos * 64
                                                  + (hoff ^ ((pos & 7) << 3)));
                acc[nt] = __builtin_amdgcn_mfma_f32_16x16x32_bf16(a, b, acc[nt], 0, 0, 0);
            }
        }
        __syncthreads();   // all h1t + imgbf reads done; overlay region reusable
        // epilogue: D[row=quad*4+r][col=mrow] -> cbuf[cout][pos] bf16, + bias
        #pragma unroll
        for (int nt = 0; nt < 7; ++nt) {
            const int n = nt * 16 + mrow;
            if (n < 100) {
                #pragma unroll
                for (int r = 0; r < 4; ++r) {
                    const int cout = wv * 16 + quad * 4 + r;
                    cbuf[cout * 101 + n] = f2bf(acc[nt][r] + b2[cout]);
                }
            }
        }
    }
    __syncthreads();

    // ---- stage 2b: pool 3x3 s2 + relu -> h2t[pos*65+cin] fp32 ----
    {
        const short* cb = cbuf + c * 101;
        #pragma unroll
        for (int k = 0; k < 4; ++k) {
            const int pos = q * 4 + k;
            const int py = pos >> 2, px = pos & 3;
            float m = -1e30f;
            #pragma unroll
            for (int a = 0; a < 3; ++a)
                #pragma unroll
                for (int b = 0; b < 3; ++b)
                    m = fmaxf(m, bf2f(cb[(2 * py + a) * 10 + (2 * px + b)]));
            h2t[pos * 65 + c] = fmaxf(m, 0.0f);
        }
    }
    __syncthreads();

    // ---- stage 3: conv3 4x4 -> out[n][10] ----
    if (t < 160) {
        const int o = t >> 4, l = t & 15;
        const float* w3o = w3 + o * 1024;
        float s = 0.0f;
        #pragma unroll
        for (int cc = 0; cc < 4; ++cc) {
            const int cin = l * 4 + cc;
            const float4 wv4a = *(const float4*)(w3o + cin * 16);
            const float4 wv4b = *(const float4*)(w3o + cin * 16 + 4);
            const float4 wv4c = *(const float4*)(w3o + cin * 16 + 8);
            const float4 wv4d = *(const float4*)(w3o + cin * 16 + 12);
            const float* hh = h2t + cin;           // h2t[k*65+cin]
            s += hh[0*65] * wv4a.x + hh[1*65] * wv4a.y + hh[2*65] * wv4a.z + hh[3*65] * wv4a.w;
            s += hh[4*65] * wv4b.x + hh[5*65] * wv4b.y + hh[6*65] * wv4b.z + hh[7*65] * wv4b.w;
            s += hh[8*65] * wv4c.x + hh[9*65] * wv4c.y + hh[10*65] * wv4c.z + hh[11*65] * wv4c.w;
            s += hh[12*65] * wv4d.x + hh[13*65] * wv4d.y + hh[14*65] * wv4d.z + hh[15*65] * wv4d.w;
        }
        prt[t] = s;   // cbuf dead (pool reads barriered above)
    }
    __syncthreads();
    if (t < 10) {
        float s = b3[t];
        #pragma unroll
        for (int l = 0; l < 16; ++l) s += prt[t * 16 + l];
        out[(size_t)n_img * 10 + t] = s;
    }
}

extern "C" void kernel_launch(void* const* d_in, const int* in_sizes, int n_in,
                              void* d_out, int out_size, void* d_ws, size_t ws_size,
                              hipStream_t stream) {
    const float* x  = (const float*)d_in[0];
    const float* w1 = (const float*)d_in[1];
    const float* b1 = (const float*)d_in[2];
    const float* w2 = (const float*)d_in[3];
    const float* b2 = (const float*)d_in[4];
    const float* w3 = (const float*)d_in[5];
    const float* b3 = (const float*)d_in[6];
    float* out = (float*)d_out;
    short* w2r = (short*)d_ws;            // 36864 bf16 = 73728 B

    const int B = in_sizes[0] / 784;      // 2048
    prep_w2<<<144, 256, 0, stream>>>(w2, w2r);
    convnet_fused<<<B, 256, 0, stream>>>(x, w1, b1, w2r, b2, w3, b3, out);
}

// Round 5
// 155.736 us; speedup vs baseline: 1.1927x; 1.1927x over previous
//
#include <hip/hip_runtime.h>

// Fused CNN, conv2 via bf16 MFMA (16x16x32).
// R8: R3 structure (proven 52us, 64 VGPR, 5 blocks/CU) with stage-2 wave
//     mapping flipped from M-split to N-split.
//     Theory: in R3 each of 4 waves re-read the ENTIRE h1t B-panel
//     (144 b128 LDS reads/wave, 576/block ~ 23us of LDS pipe across the
//     8 sequential blocks/CU) - the largest single cost, bigger than
//     stage-1 VALU (~13us). N-split: each wave = all 64 couts x 32
//     positions (N pad 128, 2 n-tiles/wave) -> 36 b128 LDS reads/wave
//     (4x less). A (w2r) becomes 72 global dwordx4/wave on the idle VMEM
//     pipe (w2r = 72KB, L1/L2 resident; HBM is at 1%).
//     R7 lesson: never force occupancy via launch_bounds min-waves (spills:
//     255MB scratch). R4/R6 lesson: VGPR must stay <=64 naturally.
//     Keeps R4's verified bank fixes: cbuf stride 101, h2t stride 65.

typedef __attribute__((ext_vector_type(8))) short short8;   // 8 x bf16 (4 VGPRs)
typedef __attribute__((ext_vector_type(4))) float f32x4;

__device__ inline short f2bf(float f) {   // fp32 -> bf16, round-to-nearest-even
    union { float f; unsigned u; } v; v.f = f;
    unsigned r = (v.u + 0x7FFFu + ((v.u >> 16) & 1u)) >> 16;
    return (short)r;
}

// w2r[s][cout][cin] (bf16), s = ky*3+kx: MFMA A-fragments contiguous in cin.
__global__ __launch_bounds__(256) void prep_w2(const float* __restrict__ w2,
                                               short* __restrict__ w2r) {
    int i = blockIdx.x * 256 + threadIdx.x;      // 9*64*64 = 36864
    if (i >= 36864) return;
    int s = i >> 12, cout = (i >> 6) & 63, cin = i & 63;
    w2r[i] = f2bf(w2[cout * 576 + cin * 9 + s]);
}

__global__ __launch_bounds__(256) void convnet_fused(
    const float* __restrict__ x,   // [B,1,28,28]
    const float* __restrict__ w1,  // [64,1,3,3]
    const float* __restrict__ b1,  // [64]
    const short* __restrict__ w2r, // [9][64][64] bf16 (prep)
    const float* __restrict__ b2,  // [64]
    const float* __restrict__ w3,  // [10,64,4,4]
    const float* __restrict__ b3,  // [10]
    float* __restrict__ out)       // [B,10]
{
    // Overlay plan (floats):
    //   [0..5184)    h1t bf16 [144 pos][72 cin-stride]  -> later cbuf fp32 [64][101] ([0..6464))
    //   [5184..5968) img 28x28                          -> (absorbed by cbuf)
    //   [6464..7504) h2t fp32 [16 pos][65 stride]
    //   [0..160)     stage-3 partials (cbuf dead by then)
    __shared__ float lds_f[7504];                // 30016 B -> 5 blocks/CU
    short* h1t  = (short*)lds_f;
    float* img  = lds_f + 5184;
    float* cbuf = lds_f;                         // conv2buf fp32 [64][101]
    float* h2t  = lds_f + 6464;
    float* prt  = lds_f;

    const int n_img = blockIdx.x;
    const int t = threadIdx.x;
    const int c = t >> 2;        // 0..63
    const int q = t & 3;         // quadrant

    // ---- load input image ----
    const float* img_g = x + (size_t)n_img * 784;
    for (int i = t; i < 784; i += 256) img[i] = img_g[i];
    __syncthreads();

    // ---- stage 1: conv1 + pool 3x3 s2 + relu -> h1t[pos][c] (bf16), no recompute ----
    {
        const int oy = (q >> 1) * 6, ox = (q & 1) * 6;   // pooled quadrant origin
        const int iy0 = 2 * oy, ix0 = 2 * ox;            // input/conv region origin
        float w[9];
        #pragma unroll
        for (int k = 0; k < 9; ++k) w[k] = w1[c * 9 + k];
        const float bias = b1[c];

        float in0[15], in1[15], in2[15];                 // ring of 3 input rows
        #pragma unroll
        for (int s = 0; s < 15; ++s) in0[s] = img[(iy0 + 0) * 28 + ix0 + s];
        #pragma unroll
        for (int s = 0; s < 15; ++s) in1[s] = img[(iy0 + 1) * 28 + ix0 + s];
        float cm[3][6];                                  // colmax ring (3 conv rows)

        #pragma unroll
        for (int r = 0; r < 13; ++r) {                   // conv rows, computed once
            #pragma unroll
            for (int s = 0; s < 15; ++s) in2[s] = img[(iy0 + r + 2) * 28 + ix0 + s];
            #pragma unroll
            for (int px = 0; px < 6; ++px) cm[r % 3][px] = -1e30f;
            #pragma unroll
            for (int xx = 0; xx < 13; ++xx) {
                float a = bias;
                #pragma unroll
                for (int j = 0; j < 3; ++j) {
                    a += in0[xx + j] * w[j];
                    a += in1[xx + j] * w[3 + j];
                    a += in2[xx + j] * w[6 + j];
                }
                // fold conv value into colmax: px with 2px <= xx <= 2px+2
                if ((xx & 1) == 0) {
                    if (xx >= 2 && xx <= 12) cm[r % 3][xx / 2 - 1] = fmaxf(cm[r % 3][xx / 2 - 1], a);
                    if (xx <= 10)            cm[r % 3][xx / 2]     = fmaxf(cm[r % 3][xx / 2], a);
                } else {
                    cm[r % 3][xx / 2] = fmaxf(cm[r % 3][xx / 2], a);
                }
            }
            if (r >= 2 && (r & 1) == 0) {                // pooled row py = r/2 - 1 complete
                const int py = r / 2 - 1;
                #pragma unroll
                for (int px = 0; px < 6; ++px) {
                    float m = fmaxf(fmaxf(cm[0][px], cm[1][px]), cm[2][px]);
                    h1t[((oy + py) * 12 + ox + px) * 72 + c] = f2bf(fmaxf(m, 0.0f));
                }
            }
            #pragma unroll
            for (int s = 0; s < 15; ++s) { in0[s] = in1[s]; in1[s] = in2[s]; }
        }
    }
    __syncthreads();

    // ---- stage 2: conv2 as MFMA GEMM, N-split over waves ----
    // M=64 cout (4 m-tiles, all waves), N=128 pad (wave wv owns n-tiles 2wv,2wv+1),
    // K=576. B (h1t) read once per (ks,nt): 36 b128/wave. A (w2r) from global.
    const int wv = t >> 6, lane = t & 63;
    const int quad = lane >> 4, mrow = lane & 15;
    {
        int base_el[2];
        #pragma unroll
        for (int nt = 0; nt < 2; ++nt) {
            int n = (wv * 2 + nt) * 16 + mrow;
            if (n > 99) n = 99;                           // clamp pad cols (discarded)
            int y = n / 10, xx = n - y * 10;
            base_el[nt] = (y * 12 + xx) * 72;
        }
        f32x4 acc[4][2];
        #pragma unroll
        for (int mt = 0; mt < 4; ++mt)
            #pragma unroll
            for (int nt = 0; nt < 2; ++nt) acc[mt][nt] = (f32x4){0.f, 0.f, 0.f, 0.f};

        #pragma unroll
        for (int ks = 0; ks < 18; ++ks) {
            const int s = ks >> 1, h = ks & 1;
            const int ky = s / 3, kx = s - ky * 3;
            const int koff = (ky * 12 + kx) * 72 + h * 32 + quad * 8;
            const short8 b0 = *(const short8*)(h1t + base_el[0] + koff);
            const short8 b1v = *(const short8*)(h1t + base_el[1] + koff);
            #pragma unroll
            for (int mt = 0; mt < 4; ++mt) {
                const short8 a = *(const short8*)(w2r + s * 4096 + (mt * 16 + mrow) * 64
                                                  + h * 32 + quad * 8);
                acc[mt][0] = __builtin_amdgcn_mfma_f32_16x16x32_bf16(a, b0, acc[mt][0], 0, 0, 0);
                acc[mt][1] = __builtin_amdgcn_mfma_f32_16x16x32_bf16(a, b1v, acc[mt][1], 0, 0, 0);
            }
        }
        __syncthreads();   // all h1t + img reads done; overlay region reusable
        // epilogue: D[row=quad*4+r (within m-tile)][col=mrow] -> cbuf[cout][n] + bias
        #pragma unroll
        for (int nt = 0; nt < 2; ++nt) {
            const int n = (wv * 2 + nt) * 16 + mrow;
            if (n < 100) {
                #pragma unroll
                for (int mt = 0; mt < 4; ++mt) {
                    #pragma unroll
                    for (int r = 0; r < 4; ++r) {
                        const int cout = mt * 16 + quad * 4 + r;
                        cbuf[cout * 101 + n] = acc[mt][nt][r] + b2[cout];
                    }
                }
            }
        }
    }
    __syncthreads();

    // ---- stage 2b: pool 3x3 s2 + relu -> h2t[pos*65+cin] fp32 ----
    {
        const float* cb = cbuf + c * 101;
        #pragma unroll
        for (int k = 0; k < 4; ++k) {
            const int pos = q * 4 + k;
            const int py = pos >> 2, px = pos & 3;
            float m = -1e30f;
            #pragma unroll
            for (int a = 0; a < 3; ++a)
                #pragma unroll
                for (int b = 0; b < 3; ++b)
                    m = fmaxf(m, cb[(2 * py + a) * 10 + (2 * px + b)]);
            h2t[pos * 65 + c] = fmaxf(m, 0.0f);
        }
    }
    __syncthreads();

    // ---- stage 3: conv3 4x4 -> out[n][10] ----
    if (t < 160) {
        const int o = t >> 4, l = t & 15;
        const float* w3o = w3 + o * 1024;
        float s = 0.0f;
        #pragma unroll
        for (int cc = 0; cc < 4; ++cc) {
            const int cin = l * 4 + cc;
            const float4 wv4a = *(const float4*)(w3o + cin * 16);
            const float4 wv4b = *(const float4*)(w3o + cin * 16 + 4);
            const float4 wv4c = *(const float4*)(w3o + cin * 16 + 8);
            const float4 wv4d = *(const float4*)(w3o + cin * 16 + 12);
            const float* hh = h2t + cin;           // h2t[k*65+cin]
            s += hh[0*65] * wv4a.x + hh[1*65] * wv4a.y + hh[2*65] * wv4a.z + hh[3*65] * wv4a.w;
            s += hh[4*65] * wv4b.x + hh[5*65] * wv4b.y + hh[6*65] * wv4b.z + hh[7*65] * wv4b.w;
            s += hh[8*65] * wv4c.x + hh[9*65] * wv4c.y + hh[10*65] * wv4c.z + hh[11*65] * wv4c.w;
            s += hh[12*65] * wv4d.x + hh[13*65] * wv4d.y + hh[14*65] * wv4d.z + hh[15*65] * wv4d.w;
        }
        prt[t] = s;   // cbuf dead (pool reads barriered above)
    }
    __syncthreads();
    if (t < 10) {
        float s = b3[t];
        #pragma unroll
        for (int l = 0; l < 16; ++l) s += prt[t * 16 + l];
        out[(size_t)n_img * 10 + t] = s;
    }
}

extern "C" void kernel_launch(void* const* d_in, const int* in_sizes, int n_in,
                              void* d_out, int out_size, void* d_ws, size_t ws_size,
                              hipStream_t stream) {
    const float* x  = (const float*)d_in[0];
    const float* w1 = (const float*)d_in[1];
    const float* b1 = (const float*)d_in[2];
    const float* w2 = (const float*)d_in[3];
    const float* b2 = (const float*)d_in[4];
    const float* w3 = (const float*)d_in[5];
    const float* b3 = (const float*)d_in[6];
    float* out = (float*)d_out;
    short* w2r = (short*)d_ws;            // 36864 bf16 = 73728 B

    const int B = in_sizes[0] / 784;      // 2048
    prep_w2<<<144, 256, 0, stream>>>(w2, w2r);
    convnet_fused<<<B, 256, 0, stream>>>(x, w1, b1, w2r, b2, w3, b3, out);
}

// Round 6
// 114.693 us; speedup vs baseline: 1.6195x; 1.3579x over previous
//
#include <hip/hip_runtime.h>

// Fused CNN, conv2 via bf16 MFMA (16x16x32).
// R9: recombination of ONLY the individually-verified pieces:
//   - R3 stage-1 scalar ring, byte-identical (the one variant proven to
//     allocate 64 VGPR; R4/R6/R8 drifted to 72-80 = 4-waves/SIMD cliff).
//   - R7's h1t stride 72->64 shorts + XOR swizzle (c ^ (pos&7)<<3): passed
//     harness, cut SQ_LDS_BANK_CONFLICT 8.76M -> 4.74M.
//   - R6's cbuf bf16 [64][101] (passed; stride 101 from R4).
//   Peak LDS = h1t 18432 + img fp32 3136 = 21568 B -> 7 blocks/CU at
//   VGPR<=64 (was 5). Stage-2 overlay cbuf+h2t = 17088 B fits in dead h1t.
//   R7 lesson: NEVER force min-waves. R8 lesson: keep A loads at 18/lane.

typedef __attribute__((ext_vector_type(8))) short short8;   // 8 x bf16 (4 VGPRs)
typedef __attribute__((ext_vector_type(4))) float f32x4;

__device__ inline short f2bf(float f) {   // fp32 -> bf16, round-to-nearest-even
    union { float f; unsigned u; } v; v.f = f;
    unsigned r = (v.u + 0x7FFFu + ((v.u >> 16) & 1u)) >> 16;
    return (short)r;
}
__device__ inline float bf2f(short s) {
    union { unsigned u; float f; } v; v.u = ((unsigned)(unsigned short)s) << 16;
    return v.f;
}

// w2r[s][cout][cin] (bf16), s = ky*3+kx: MFMA A-fragments contiguous in cin.
__global__ __launch_bounds__(256) void prep_w2(const float* __restrict__ w2,
                                               short* __restrict__ w2r) {
    int i = blockIdx.x * 256 + threadIdx.x;      // 9*64*64 = 36864
    if (i >= 36864) return;
    int s = i >> 12, cout = (i >> 6) & 63, cin = i & 63;
    w2r[i] = f2bf(w2[cout * 576 + cin * 9 + s]);
}

__global__ __launch_bounds__(256) void convnet_fused(
    const float* __restrict__ x,   // [B,1,28,28]
    const float* __restrict__ w1,  // [64,1,3,3]
    const float* __restrict__ b1,  // [64]
    const short* __restrict__ w2r, // [9][64][64] bf16 (prep)
    const float* __restrict__ b2,  // [64]
    const float* __restrict__ w3,  // [10,64,4,4]
    const float* __restrict__ b3,  // [10]
    float* __restrict__ out)       // [B,10]
{
    // Overlay plan (bytes):
    //   [0..18432)      h1t bf16 [144 pos][64 cin], XOR-swizzled (pos&7)<<3
    //   [18432..21568)  img fp32 28x28
    //   stage2+ (h1t/img dead after mid-stage-2 barrier):
    //   [0..12928)      cbuf bf16 [64][101]
    //   [12928..17088)  h2t fp32 [16 pos][65 stride]
    //   [0..640)        stage-3 partials (cbuf dead by then)
    __shared__ float lds_f[5392];                // 21568 B -> 7 blocks/CU
    short* h1t  = (short*)lds_f;
    float* img  = lds_f + 4608;
    short* cbuf = (short*)lds_f;                 // bf16 [64][101]
    float* h2t  = lds_f + 3232;
    float* prt  = lds_f;

    const int n_img = blockIdx.x;
    const int t = threadIdx.x;
    const int c = t >> 2;        // 0..63
    const int q = t & 3;         // quadrant

    // ---- load input image ----
    const float* img_g = x + (size_t)n_img * 784;
    for (int i = t; i < 784; i += 256) img[i] = img_g[i];
    __syncthreads();

    // ---- stage 1: conv1 + pool 3x3 s2 + relu -> h1t[pos][c] (bf16), no recompute ----
    {
        const int oy = (q >> 1) * 6, ox = (q & 1) * 6;   // pooled quadrant origin
        const int iy0 = 2 * oy, ix0 = 2 * ox;            // input/conv region origin
        float w[9];
        #pragma unroll
        for (int k = 0; k < 9; ++k) w[k] = w1[c * 9 + k];
        const float bias = b1[c];

        float in0[15], in1[15], in2[15];                 // ring of 3 input rows
        #pragma unroll
        for (int s = 0; s < 15; ++s) in0[s] = img[(iy0 + 0) * 28 + ix0 + s];
        #pragma unroll
        for (int s = 0; s < 15; ++s) in1[s] = img[(iy0 + 1) * 28 + ix0 + s];
        float cm[3][6];                                  // colmax ring (3 conv rows)

        #pragma unroll
        for (int r = 0; r < 13; ++r) {                   // conv rows, computed once
            #pragma unroll
            for (int s = 0; s < 15; ++s) in2[s] = img[(iy0 + r + 2) * 28 + ix0 + s];
            #pragma unroll
            for (int px = 0; px < 6; ++px) cm[r % 3][px] = -1e30f;
            #pragma unroll
            for (int xx = 0; xx < 13; ++xx) {
                float a = bias;
                #pragma unroll
                for (int j = 0; j < 3; ++j) {
                    a += in0[xx + j] * w[j];
                    a += in1[xx + j] * w[3 + j];
                    a += in2[xx + j] * w[6 + j];
                }
                // fold conv value into colmax: px with 2px <= xx <= 2px+2
                if ((xx & 1) == 0) {
                    if (xx >= 2 && xx <= 12) cm[r % 3][xx / 2 - 1] = fmaxf(cm[r % 3][xx / 2 - 1], a);
                    if (xx <= 10)            cm[r % 3][xx / 2]     = fmaxf(cm[r % 3][xx / 2], a);
                } else {
                    cm[r % 3][xx / 2] = fmaxf(cm[r % 3][xx / 2], a);
                }
            }
            if (r >= 2 && (r & 1) == 0) {                // pooled row py = r/2 - 1 complete
                const int py = r / 2 - 1;
                #pragma unroll
                for (int px = 0; px < 6; ++px) {
                    float m = fmaxf(fmaxf(cm[0][px], cm[1][px]), cm[2][px]);
                    const int pos = (oy + py) * 12 + ox + px;
                    h1t[pos * 64 + (c ^ ((pos & 7) << 3))] = f2bf(fmaxf(m, 0.0f));
                }
            }
            #pragma unroll
            for (int s = 0; s < 15; ++s) { in0[s] = in1[s]; in1[s] = in2[s]; }
        }
    }
    __syncthreads();

    // ---- stage 2: conv2 as MFMA GEMM (M=64 cout, N=100 pad 112, K=576) ----
    const int wv = t >> 6, lane = t & 63;
    const int quad = lane >> 4, mrow = lane & 15;
    {
        int pos_b[7];
        #pragma unroll
        for (int nt = 0; nt < 7; ++nt) {
            int n = nt * 16 + mrow; if (n > 99) n = 99;   // clamp pad cols (discarded)
            int y = n / 10, xx = n - y * 10;
            pos_b[nt] = y * 12 + xx;
        }
        f32x4 acc[7];
        #pragma unroll
        for (int nt = 0; nt < 7; ++nt) acc[nt] = (f32x4){0.f, 0.f, 0.f, 0.f};

        #pragma unroll
        for (int ks = 0; ks < 18; ++ks) {
            const int s = ks >> 1, h = ks & 1;
            const int ky = s / 3, kx = s - ky * 3;
            const int koff = ky * 12 + kx;
            const int hoff = h * 32 + quad * 8;
            const short8 a = *(const short8*)(w2r + s * 4096 + (wv * 16 + mrow) * 64
                                              + h * 32 + quad * 8);
            #pragma unroll
            for (int nt = 0; nt < 7; ++nt) {
                const int pos = pos_b[nt] + koff;
                const short8 b = *(const short8*)(h1t + pos * 64
                                                  + (hoff ^ ((pos & 7) << 3)));
                acc[nt] = __builtin_amdgcn_mfma_f32_16x16x32_bf16(a, b, acc[nt], 0, 0, 0);
            }
        }
        __syncthreads();   // all h1t + img reads done; overlay region reusable
        // epilogue: D[row=quad*4+r][col=mrow] -> cbuf[cout][pos] bf16, + bias
        #pragma unroll
        for (int nt = 0; nt < 7; ++nt) {
            const int n = nt * 16 + mrow;
            if (n < 100) {
                #pragma unroll
                for (int r = 0; r < 4; ++r) {
                    const int cout = wv * 16 + quad * 4 + r;
                    cbuf[cout * 101 + n] = f2bf(acc[nt][r] + b2[cout]);
                }
            }
        }
    }
    __syncthreads();

    // ---- stage 2b: pool 3x3 s2 + relu -> h2t[pos*65+cin] fp32 ----
    {
        const short* cb = cbuf + c * 101;
        #pragma unroll
        for (int k = 0; k < 4; ++k) {
            const int pos = q * 4 + k;
            const int py = pos >> 2, px = pos & 3;
            float m = -1e30f;
            #pragma unroll
            for (int a = 0; a < 3; ++a)
                #pragma unroll
                for (int b = 0; b < 3; ++b)
                    m = fmaxf(m, bf2f(cb[(2 * py + a) * 10 + (2 * px + b)]));
            h2t[pos * 65 + c] = fmaxf(m, 0.0f);
        }
    }
    __syncthreads();

    // ---- stage 3: conv3 4x4 -> out[n][10] ----
    if (t < 160) {
        const int o = t >> 4, l = t & 15;
        const float* w3o = w3 + o * 1024;
        float s = 0.0f;
        #pragma unroll
        for (int cc = 0; cc < 4; ++cc) {
            const int cin = l * 4 + cc;
            const float4 wv4a = *(const float4*)(w3o + cin * 16);
            const float4 wv4b = *(const float4*)(w3o + cin * 16 + 4);
            const float4 wv4c = *(const float4*)(w3o + cin * 16 + 8);
            const float4 wv4d = *(const float4*)(w3o + cin * 16 + 12);
            const float* hh = h2t + cin;           // h2t[k*65+cin]
            s += hh[0*65] * wv4a.x + hh[1*65] * wv4a.y + hh[2*65] * wv4a.z + hh[3*65] * wv4a.w;
            s += hh[4*65] * wv4b.x + hh[5*65] * wv4b.y + hh[6*65] * wv4b.z + hh[7*65] * wv4b.w;
            s += hh[8*65] * wv4c.x + hh[9*65] * wv4c.y + hh[10*65] * wv4c.z + hh[11*65] * wv4c.w;
            s += hh[12*65] * wv4d.x + hh[13*65] * wv4d.y + hh[14*65] * wv4d.z + hh[15*65] * wv4d.w;
        }
        prt[t] = s;   // cbuf dead (pool reads barriered above)
    }
    __syncthreads();
    if (t < 10) {
        float s = b3[t];
        #pragma unroll
        for (int l = 0; l < 16; ++l) s += prt[t * 16 + l];
        out[(size_t)n_img * 10 + t] = s;
    }
}

extern "C" void kernel_launch(void* const* d_in, const int* in_sizes, int n_in,
                              void* d_out, int out_size, void* d_ws, size_t ws_size,
                              hipStream_t stream) {
    const float* x  = (const float*)d_in[0];
    const float* w1 = (const float*)d_in[1];
    const float* b1 = (const float*)d_in[2];
    const float* w2 = (const float*)d_in[3];
    const float* b2 = (const float*)d_in[4];
    const float* w3 = (const float*)d_in[5];
    const float* b3 = (const float*)d_in[6];
    float* out = (float*)d_out;
    short* w2r = (short*)d_ws;            // 36864 bf16 = 73728 B

    const int B = in_sizes[0] / 784;      // 2048
    prep_w2<<<144, 256, 0, stream>>>(w2, w2r);
    convnet_fused<<<B, 256, 0, stream>>>(x, w1, b1, w2r, b2, w3, b3, out);
}